// Round 5
// baseline (116.378 us; speedup 1.0000x reference)
//
#include <hip/hip_runtime.h>

// ifft(fft(x)) == x (identity). Output = out_size float32 == input count ->
// pure 268 MB identity copy, memory-bound.
//
// Round-4 post-mortem: single-load grid-stride copy = 5.34 TB/s (100.4 us),
// 15% under the m13 float4-copy ceiling (6.29 TB/s). Theory: 1 outstanding
// load per wave limits MLP. Fix: 4x unroll with independent loads (all 4
// issued before the stores), 4x in-flight bytes per wave. Coalescing is
// preserved (adjacent lanes adjacent addresses at each of the 4 offsets).

typedef float vfloat4 __attribute__((ext_vector_type(4)));

__global__ __launch_bounds__(256) void identity_copy_f4x4(
        const vfloat4* __restrict__ in4,
        vfloat4* __restrict__ out4,
        long n4) {
    long tid    = (long)blockIdx.x * blockDim.x + threadIdx.x;
    long stride = (long)gridDim.x * blockDim.x;

    long i = tid;
    for (; i + 3 * stride < n4; i += 4 * stride) {
        vfloat4 v0 = __builtin_nontemporal_load(&in4[i]);
        vfloat4 v1 = __builtin_nontemporal_load(&in4[i + stride]);
        vfloat4 v2 = __builtin_nontemporal_load(&in4[i + 2 * stride]);
        vfloat4 v3 = __builtin_nontemporal_load(&in4[i + 3 * stride]);
        __builtin_nontemporal_store(v0, &out4[i]);
        __builtin_nontemporal_store(v1, &out4[i + stride]);
        __builtin_nontemporal_store(v2, &out4[i + 2 * stride]);
        __builtin_nontemporal_store(v3, &out4[i + 3 * stride]);
    }
    for (; i < n4; i += stride) {
        vfloat4 v = __builtin_nontemporal_load(&in4[i]);
        __builtin_nontemporal_store(v, &out4[i]);
    }
}

extern "C" void kernel_launch(void* const* d_in, const int* in_sizes, int n_in,
                              void* d_out, int out_size, void* d_ws, size_t ws_size,
                              hipStream_t stream) {
    const float* x = (const float*)d_in[0];
    float* out = (float*)d_out;

    long n_input = (long)in_sizes[0];   // 67,108,864 floats
    long n_out   = (long)out_size;
    long n_copy  = n_out < n_input ? n_out : n_input;

    long n4   = n_copy / 4;
    long tail = n_copy - n4 * 4;

    int block = 256;
    long total_blocks = (n4 + block - 1) / block;
    int grid = (int)(total_blocks < 2048 ? total_blocks : 2048);

    identity_copy_f4x4<<<grid, block, 0, stream>>>(
        (const vfloat4*)x, (vfloat4*)out, n4);

    if (tail > 0) {
        (void)hipMemcpyAsync(out + n4 * 4, x + n4 * 4,
                             (size_t)tail * sizeof(float),
                             hipMemcpyDeviceToDevice, stream);
    }
}

// Round 6
// 86.616 us; speedup vs baseline: 1.3436x; 1.3436x over previous
//
#include <hip/hip_runtime.h>

// ifft(fft(x)) == x (identity). Output = out_size float32 == input count ->
// pure 268 MB identity copy, memory-bound.
//
// Round-5 post-mortem: 4x-unrolled grid-stride REGRESSED (100.4 -> 116.4 us).
// MLP-per-wave wasn't the limiter; wave-level parallelism (32 waves/CU)
// already covers latency. Revised theory: grid-stride loop overhead and
// bunched store bursts hurt. m13-style config instead: ONE float4 per
// thread, exact grid, no loop. 65,536 blocks x 256 threads covers
// 16,777,216 float4s exactly.

typedef float vfloat4 __attribute__((ext_vector_type(4)));

__global__ __launch_bounds__(256) void identity_copy_1to1(
        const vfloat4* __restrict__ in4,
        vfloat4* __restrict__ out4,
        long n4) {
    long i = (long)blockIdx.x * blockDim.x + threadIdx.x;
    if (i < n4) {
        vfloat4 v = __builtin_nontemporal_load(&in4[i]);
        __builtin_nontemporal_store(v, &out4[i]);
    }
}

extern "C" void kernel_launch(void* const* d_in, const int* in_sizes, int n_in,
                              void* d_out, int out_size, void* d_ws, size_t ws_size,
                              hipStream_t stream) {
    const float* x = (const float*)d_in[0];
    float* out = (float*)d_out;

    long n_input = (long)in_sizes[0];   // 67,108,864 floats
    long n_out   = (long)out_size;
    long n_copy  = n_out < n_input ? n_out : n_input;

    long n4   = n_copy / 4;             // 16,777,216 float4s
    long tail = n_copy - n4 * 4;

    int block = 256;
    long grid = (n4 + block - 1) / block;   // 65,536 blocks

    identity_copy_1to1<<<(int)grid, block, 0, stream>>>(
        (const vfloat4*)x, (vfloat4*)out, n4);

    if (tail > 0) {
        (void)hipMemcpyAsync(out + n4 * 4, x + n4 * 4,
                             (size_t)tail * sizeof(float),
                             hipMemcpyDeviceToDevice, stream);
    }
}